// Round 8
// baseline (80.023 us; speedup 1.0000x reference)
//
#include <hip/hip_runtime.h>
#include <hip/hip_bf16.h>

#define NS   16384
#define FKD  2048
#define CD   100
#define CP   112
#define MT   256                 // m-columns per block tile (1KB fp32 rows -> contiguous staging)
#define ROWS 32                  // n-rows staged per phase (= one k=32 MFMA step)
#define EPSF 1e-8f
#define SFK  (FKD * CP)          // 229376 elements of one S partial
#define NGRP (NS / 8)            // 2048 k-groups of 8

typedef float f32x4 __attribute__((ext_vector_type(4)));
typedef short bf16x8 __attribute__((ext_vector_type(8)));

__device__ inline unsigned short f2bf(float f) {
    unsigned int u = __float_as_uint(f);
    u += 0x7FFFu + ((u >> 16) & 1u);   // RNE; inputs are finite in [0,1]
    return (unsigned short)(u >> 16);
}

__device__ __forceinline__ void gload16(const float* g, float* l) {
    __builtin_amdgcn_global_load_lds(
        (const __attribute__((address_space(1))) void*)g,
        (__attribute__((address_space(3))) void*)l, 16, 0, 0);
}

// ---------------- prep: teacher -> bf16 fragment layout ----------------
// Bp[g][c][j] = bf16(tp[(8g+j)*CD + c]) ; col CD == 1.0 (bin-mass column), >CD == 0
__global__ __launch_bounds__(256) void ebl_prep(
    const float* __restrict__ tp, unsigned short* __restrict__ Bp)
{
    const int idx = blockIdx.x * 256 + threadIdx.x;     // (g, c)
    if (idx >= NGRP * CP) return;
    const int g = idx / CP, c = idx - g * CP;
    unsigned short v[8];
    if (c < CD) {
        const float* p = tp + (size_t)g * 8 * CD + c;
        #pragma unroll
        for (int j = 0; j < 8; ++j) v[j] = f2bf(p[(size_t)j * CD]);
    } else {
        const unsigned short fill = (c == CD) ? 0x3F80 : 0;   // bf16(1.0) / 0
        #pragma unroll
        for (int j = 0; j < 8; ++j) v[j] = fill;
    }
    *reinterpret_cast<uint4*>(Bp + (size_t)idx * 8) = *reinterpret_cast<const uint4*>(v);
}

// ---------------- GEMM: 256-wide tile, 1KB-contiguous global_load_lds staging ----------------
// S_partial[kc][m][c] (bf16) = sum over k-chunk of bf16(mem[n][m]) * Bp[n][c]
__global__ __launch_bounds__(256, 2) void ebl_gemm(
    const float* __restrict__ mem, const unsigned short* __restrict__ Bp,
    unsigned short* __restrict__ spart, int steps)
{
    __shared__ float At[2][ROWS * MT];    // 2 x 32 KB, [row][256] linear

    const int t  = threadIdx.x;
    const int w  = t >> 6;                 // wave -> m columns [w*64, w*64+64)
    const int l  = t & 63;
    const int lg = l >> 4, lr = l & 15;
    const int m0 = blockIdx.x * MT;
    const int kc = blockIdx.y;
    const int n0 = kc * steps * ROWS;      // first n-row of this k-chunk
    const int gb = n0 >> 3;                // first k-group (of 8 rows)

    f32x4 acc[4][7];
    #pragma unroll
    for (int i = 0; i < 4; ++i)
        #pragma unroll
        for (int nt = 0; nt < 7; ++nt) acc[i][nt] = (f32x4){0.f, 0.f, 0.f, 0.f};

    // STAGE: one instr = one full 1KB tile-row (lane l -> bytes l*16..l*16+15).
    // LDS dest wave-uniform; HW lane-offset i*16 lands exactly at At[row][l*4..l*4+3].
#define STAGE(buf, nbase) { \
    _Pragma("unroll") \
    for (int q = 0; q < 8; ++q) { \
        const int rr = w * 8 + q; \
        gload16(mem + (size_t)((nbase) + rr) * FKD + m0 + l * 4, \
                &At[buf][rr * MT]); } }

    STAGE(0, n0)

    for (int ph = 0; ph < steps; ++ph) {
        const int cur = ph & 1;
        __syncthreads();                       // publishes stage(ph), closes reads of buf cur^1
        if (ph + 1 < steps) STAGE(cur ^ 1, n0 + (ph + 1) * ROWS)

        // B fragments: loaded once, reused for all 4 m-frags
        const unsigned short* bq = Bp + ((size_t)(gb + ph * 4 + lg) * CP + lr) * 8;
        bf16x8 bf[7];
        #pragma unroll
        for (int nt = 0; nt < 7; ++nt)
            bf[nt] = *reinterpret_cast<const bf16x8*>(bq + nt * 128);

        bf16x8 af[4];
        #pragma unroll
        for (int i = 0; i < 4; ++i)
            #pragma unroll
            for (int j = 0; j < 8; ++j)
                af[i][j] = (short)f2bf(At[cur][(lg * 8 + j) * MT + w * 64 + i * 16 + lr]);

        #pragma unroll
        for (int i = 0; i < 4; ++i)
            #pragma unroll
            for (int nt = 0; nt < 7; ++nt)
                acc[i][nt] = __builtin_amdgcn_mfma_f32_16x16x32_bf16(af[i], bf[nt], acc[i][nt], 0, 0, 0);
    }
#undef STAGE

    // C/D layout: col = lane&15, row = (lane>>4)*4 + reg   [verified rounds 1-7]
    unsigned short* sp = spart + (size_t)kc * SFK;
    #pragma unroll
    for (int i = 0; i < 4; ++i) {
        #pragma unroll
        for (int nt = 0; nt < 7; ++nt) {
            const int c = nt * 16 + lr;
            #pragma unroll
            for (int r = 0; r < 4; ++r) {
                const int mm = m0 + w * 64 + i * 16 + lg * 4 + r;
                sp[(size_t)mm * CP + c] = f2bf(acc[i][nt][r]);
            }
        }
    }
}

// ---------------- reduce split-K partials (bf16 -> fp32, parallel) ----------------
__global__ __launch_bounds__(256) void ebl_reduce(
    const unsigned short* __restrict__ spart, float* __restrict__ S, int NK)
{
    const int idx = blockIdx.x * 256 + threadIdx.x;   // uint (2-element) index
    if (idx >= SFK / 2) return;
    float s0 = 0.f, s1 = 0.f;
    for (int p = 0; p < NK; ++p) {
        const unsigned raw = *reinterpret_cast<const unsigned*>(spart + (size_t)p * SFK + (size_t)idx * 2);
        s0 += __uint_as_float(raw << 16);
        s1 += __uint_as_float(raw & 0xFFFF0000u);
    }
    *reinterpret_cast<float2*>(S + (size_t)idx * 2) = make_float2(s0, s1);
}

// ---------------- entropies per f, partial losses ----------------
__global__ __launch_bounds__(256) void ebl_entropy(
    const float* __restrict__ S, float* __restrict__ fpart)
{
    __shared__ float Ss[32 * CP];
    __shared__ float massL[32];
    __shared__ float red[4];
    const int t = threadIdx.x;
    const int f = blockIdx.x;

    for (int idx = t; idx < 32 * CP; idx += 256)
        Ss[idx] = S[(size_t)f * 32 * CP + idx];
    __syncthreads();
    if (t < 32) massL[t] = Ss[t * CP + CD] + EPSF;   // ones-column = bin mass (+EPS)
    __syncthreads();

    float a_int = 0.f, a_mix = 0.f;
    for (int idx = t; idx < 32 * CD; idx += 256) {
        const int k = idx / CD, c = idx - k * CD;
        const float cent = Ss[k * CP + c] / massL[k];
        a_int -= cent * logf(cent + EPSF) * massL[k];
    }
    for (int idx = t; idx < 31 * CD; idx += 256) {
        const int k = idx / CD, c = idx - k * CD;
        const float mix = 0.5f * (Ss[k * CP + c] / massL[k] + Ss[(k + 1) * CP + c] / massL[k + 1]);
        a_mix += mix * logf(mix + EPSF);
    }

    float part = a_int * (1.0f / (float)NS) + 0.5f * a_mix;
    #pragma unroll
    for (int off = 32; off > 0; off >>= 1) part += __shfl_down(part, off);
    if ((t & 63) == 0) red[t >> 6] = part;
    __syncthreads();
    if (t == 0) fpart[f] = (red[0] + red[1]) + (red[2] + red[3]);
}

__global__ void ebl_finalize(const float* __restrict__ fpart, float* __restrict__ out) {
    float v = fpart[threadIdx.x];
    #pragma unroll
    for (int off = 32; off > 0; off >>= 1) v += __shfl_down(v, off);
    if (threadIdx.x == 0) out[0] = v;
}

extern "C" void kernel_launch(void* const* d_in, const int* in_sizes, int n_in,
                              void* d_out, int out_size, void* d_ws, size_t ws_size,
                              hipStream_t stream)
{
    const float* mem = (const float*)d_in[0];
    const float* tp  = (const float*)d_in[1];
    float* out = (float*)d_out;

    const size_t bpBytes = (size_t)NGRP * CP * 8 * 2;    // 3,670,016 B (16-aligned)

    int NK = 64;
    while (NK > 1 &&
           bpBytes + (size_t)NK * SFK * 2 + ((size_t)SFK + 64) * 4 > ws_size) NK >>= 1;
    const int steps = NS / (NK * ROWS);   // 8 for NK=64

    unsigned short* Bp    = (unsigned short*)d_ws;
    unsigned short* spart = (unsigned short*)((char*)d_ws + bpBytes);
    float*          S     = (float*)((char*)spart + (size_t)NK * SFK * 2);
    float*          fpart = S + SFK;

    ebl_prep<<<(NGRP * CP + 255) / 256, 256, 0, stream>>>(tp, Bp);
    dim3 grid(FKD / MT, NK);
    ebl_gemm<<<grid, 256, 0, stream>>>(mem, Bp, spart, steps);
    ebl_reduce<<<(SFK / 2 + 255) / 256, 256, 0, stream>>>(spart, S, NK);
    ebl_entropy<<<64, 256, 0, stream>>>(S, fpart);
    ebl_finalize<<<1, 64, 0, stream>>>(fpart, out);
}

// Round 9
// 55.518 us; speedup vs baseline: 1.4414x; 1.4414x over previous
//
#include <hip/hip_runtime.h>
#include <hip/hip_bf16.h>

#define NS   16384
#define FKD  2048
#define CD   100
#define CP   112
#define MT   64                  // block m-tile (4 waves x 16 cols each)
#define NKC  32                  // split-K grid.y
#define PHASES 16                // (NS / NKC) / 32 rows per phase
#define EPSF 1e-8f
#define SFK  (FKD * CP)
#define NGRP (NS / 8)

typedef float f32x4 __attribute__((ext_vector_type(4)));
typedef short bf16x8 __attribute__((ext_vector_type(8)));

__device__ inline unsigned short f2bf(float f) {
    unsigned int u = __float_as_uint(f);
    u += 0x7FFFu + ((u >> 16) & 1u);   // RNE; inputs finite in [0,1]
    return (unsigned short)(u >> 16);
}

__device__ __forceinline__ void gload4(const float* g, const float* l) {
    __builtin_amdgcn_global_load_lds(
        (const __attribute__((address_space(1))) void*)g,
        (__attribute__((address_space(3))) void*)l, 4, 0, 0);
}

// ---------------- prep: teacher -> bf16 fragment layout ----------------
__global__ __launch_bounds__(256) void ebl_prep(
    const float* __restrict__ tp, unsigned short* __restrict__ Bp)
{
    const int idx = blockIdx.x * 256 + threadIdx.x;     // (g, c)
    if (idx >= NGRP * CP) return;
    const int g = idx / CP, c = idx - g * CP;
    unsigned short v[8];
    if (c < CD) {
        const float* p = tp + (size_t)g * 8 * CD + c;
        #pragma unroll
        for (int j = 0; j < 8; ++j) v[j] = f2bf(p[(size_t)j * CD]);
    } else {
        const unsigned short fill = (c == CD) ? 0x3F80 : 0;   // bf16(1.0) / 0
        #pragma unroll
        for (int j = 0; j < 8; ++j) v[j] = fill;
    }
    *reinterpret_cast<uint4*>(Bp + (size_t)idx * 8) = *reinterpret_cast<const uint4*>(v);
}

// ---------------- GEMM: wave-private 3-deep LDS pipeline, zero barriers ----------------
// Per wave-phase: 32 n-rows x 16 m-cols staged as 8 x global_load_lds(size=4),
// LDS buf = [q=8][68 dwords] (4 rows x 16 cols + 4 pad per q -> lg bank shifts {0,8,16,24}).
__global__ __launch_bounds__(256) void ebl_gemm(
    const float* __restrict__ mem, const unsigned short* __restrict__ Bp,
    unsigned short* __restrict__ spart)
{
    __shared__ float At[3 * 4 * 8 * 68];   // 3 bufs x 4 waves x 544 dwords = 26112 B

    const int t  = threadIdx.x;
    const int w  = t >> 6;
    const int l  = t & 63;
    const int lg = l >> 4, lr = l & 15;
    const int m0 = blockIdx.x * MT;
    const int kc = blockIdx.y;
    const int n0 = kc * (PHASES * 32);
    const int gb = n0 >> 3;

    // per-lane global base: row-part (l>>4), col m0 + w*16 + (l&15)
    const float* gbase = mem + (size_t)(n0 + lg) * FKD + (m0 + w * 16 + lr);

    f32x4 acc[7];
    #pragma unroll
    for (int i = 0; i < 7; ++i) acc[i] = (f32x4){0.f, 0.f, 0.f, 0.f};

    bf16x8 b0[7], b1[7];
    int o0 = (0 * 4 + w) * 544, o1 = (1 * 4 + w) * 544, o2 = (2 * 4 + w) * 544;

#define SB() __builtin_amdgcn_sched_barrier(0)
#define STAGE(bo, p) { \
    const float* gs = gbase + (size_t)(p) * 32 * FKD; \
    _Pragma("unroll") \
    for (int q = 0; q < 8; ++q) \
        gload4(gs + (size_t)q * 4 * FKD, At + (bo) + q * 68); \
    SB(); }
#define LOADB(dst, p) { \
    const unsigned short* bq = Bp + ((size_t)(gb + (p) * 4 + lg) * CP + lr) * 8; \
    _Pragma("unroll") \
    for (int nt = 0; nt < 7; ++nt) dst[nt] = *reinterpret_cast<const bf16x8*>(bq + nt * 128); \
    SB(); }
#define WAITV(n) { asm volatile("s_waitcnt vmcnt(" #n ")" ::: "memory"); SB(); }
#define COMPUTE(bo, bB) { \
    bf16x8 af; \
    _Pragma("unroll") \
    for (int j = 0; j < 8; ++j) { \
        float v = At[(bo) + (2 * lg + (j >> 2)) * 68 + (j & 3) * 16 + lr]; \
        af[j] = (short)f2bf(v); } \
    _Pragma("unroll") \
    for (int nt = 0; nt < 7; ++nt) \
        acc[nt] = __builtin_amdgcn_mfma_f32_16x16x32_bf16(af, bB[nt], acc[nt], 0, 0, 0); }

    // prologue: stage(0), B(0), stage(1)  [B(0) newer than stage(0)]
    STAGE(o0, 0)
    LOADB(b0, 0)
    STAGE(o1, 1)

    // main: phases 0..13 (by 2). Invariant at top: o0 = ph, o1 = ph+1, o2 free.
    for (int ph = 0; ph < PHASES - 2; ph += 2) {
        LOADB(b1, ph + 1)
        STAGE(o2, ph + 2)
        WAITV(23)                 // stage(ph)+B(ph) done; 2 stages + 1 B stay in flight
        COMPUTE(o0, b0)
        LOADB(b0, ph + 2)
        STAGE(o0, ph + 3)
        WAITV(23)
        COMPUTE(o1, b1)
        const int tmp = o2; o2 = o1; o1 = o0; o0 = tmp;   // (o0,o1,o2) <- (o2,o0,o1)
    }
    // epilogue: phases 14, 15  (o0 = 14, o1 = 15, b0 = B(14))
    LOADB(b1, PHASES - 1)
    WAITV(15)                     // newer-than-B(14): stage(15)=8 + B(15)=7
    COMPUTE(o0, b0)
    WAITV(0)
    COMPUTE(o1, b1)

#undef SB
#undef STAGE
#undef LOADB
#undef WAITV
#undef COMPUTE

    // C/D layout: col = lane&15, row = (lane>>4)*4 + reg   [verified rounds 1-8]
    unsigned short* sp = spart + (size_t)kc * SFK;
    #pragma unroll
    for (int nt = 0; nt < 7; ++nt) {
        const int c = nt * 16 + lr;
        #pragma unroll
        for (int r = 0; r < 4; ++r) {
            const int mm = m0 + w * 16 + lg * 4 + r;
            sp[(size_t)mm * CP + c] = f2bf(acc[nt][r]);
        }
    }
}

// ---------------- reduce split-K partials (bf16 -> fp32, parallel) ----------------
__global__ __launch_bounds__(256) void ebl_reduce(
    const unsigned short* __restrict__ spart, float* __restrict__ S)
{
    const int idx = blockIdx.x * 256 + threadIdx.x;   // 2-element index
    if (idx >= SFK / 2) return;
    float s0 = 0.f, s1 = 0.f;
    for (int p = 0; p < NKC; ++p) {
        const unsigned raw = *reinterpret_cast<const unsigned*>(spart + (size_t)p * SFK + (size_t)idx * 2);
        s0 += __uint_as_float(raw << 16);
        s1 += __uint_as_float(raw & 0xFFFF0000u);
    }
    *reinterpret_cast<float2*>(S + (size_t)idx * 2) = make_float2(s0, s1);
}

// ---------------- entropies per f, partial losses ----------------
__global__ __launch_bounds__(256) void ebl_entropy(
    const float* __restrict__ S, float* __restrict__ fpart)
{
    __shared__ float Ss[32 * CP];
    __shared__ float massL[32];
    __shared__ float red[4];
    const int t = threadIdx.x;
    const int f = blockIdx.x;

    for (int idx = t; idx < 32 * CP; idx += 256)
        Ss[idx] = S[(size_t)f * 32 * CP + idx];
    __syncthreads();
    if (t < 32) massL[t] = Ss[t * CP + CD] + EPSF;   // ones-column = bin mass (+EPS)
    __syncthreads();

    float a_int = 0.f, a_mix = 0.f;
    for (int idx = t; idx < 32 * CD; idx += 256) {
        const int k = idx / CD, c = idx - k * CD;
        const float cent = Ss[k * CP + c] / massL[k];
        a_int -= cent * logf(cent + EPSF) * massL[k];
    }
    for (int idx = t; idx < 31 * CD; idx += 256) {
        const int k = idx / CD, c = idx - k * CD;
        const float mix = 0.5f * (Ss[k * CP + c] / massL[k] + Ss[(k + 1) * CP + c] / massL[k + 1]);
        a_mix += mix * logf(mix + EPSF);
    }

    float part = a_int * (1.0f / (float)NS) + 0.5f * a_mix;
    #pragma unroll
    for (int off = 32; off > 0; off >>= 1) part += __shfl_down(part, off);
    if ((t & 63) == 0) red[t >> 6] = part;
    __syncthreads();
    if (t == 0) fpart[f] = (red[0] + red[1]) + (red[2] + red[3]);
}

__global__ void ebl_finalize(const float* __restrict__ fpart, float* __restrict__ out) {
    float v = fpart[threadIdx.x];
    #pragma unroll
    for (int off = 32; off > 0; off >>= 1) v += __shfl_down(v, off);
    if (threadIdx.x == 0) out[0] = v;
}

extern "C" void kernel_launch(void* const* d_in, const int* in_sizes, int n_in,
                              void* d_out, int out_size, void* d_ws, size_t ws_size,
                              hipStream_t stream)
{
    const float* mem = (const float*)d_in[0];
    const float* tp  = (const float*)d_in[1];
    float* out = (float*)d_out;

    const size_t bpBytes = (size_t)NGRP * CP * 8 * 2;    // 3,670,016 B

    unsigned short* Bp    = (unsigned short*)d_ws;
    unsigned short* spart = (unsigned short*)((char*)d_ws + bpBytes);
    float*          S     = (float*)((char*)spart + (size_t)NKC * SFK * 2);
    float*          fpart = S + SFK;

    ebl_prep<<<(NGRP * CP + 255) / 256, 256, 0, stream>>>(tp, Bp);
    dim3 grid(FKD / MT, NKC);                            // 32 x 32 = 1024 blocks
    ebl_gemm<<<grid, 256, 0, stream>>>(mem, Bp, spart);
    ebl_reduce<<<(SFK / 2 + 255) / 256, 256, 0, stream>>>(spart, S);
    ebl_entropy<<<64, 256, 0, stream>>>(S, fpart);
    ebl_finalize<<<1, 64, 0, stream>>>(fpart, out);
}

// Round 10
// 51.388 us; speedup vs baseline: 1.5572x; 1.0804x over previous
//
#include <hip/hip_runtime.h>
#include <hip/hip_bf16.h>

#define NS   16384
#define FKD  2048
#define CD   100
#define CP   112
#define NKC  32                  // split-K grid.y
#define PHASES 16                // (NS / NKC) / 32 rows per phase
#define EPSF 1e-8f
#define SFK  (FKD * CP)
#define NGRP (NS / 8)

typedef float f32x4 __attribute__((ext_vector_type(4)));
typedef short bf16x8 __attribute__((ext_vector_type(8)));

__device__ inline unsigned short f2bf(float f) {
    unsigned int u = __float_as_uint(f);
    u += 0x7FFFu + ((u >> 16) & 1u);   // RNE; inputs finite in [0,1]
    return (unsigned short)(u >> 16);
}

__device__ __forceinline__ void gload16(const float* g, const float* l) {
    __builtin_amdgcn_global_load_lds(
        (const __attribute__((address_space(1))) void*)g,
        (__attribute__((address_space(3))) void*)l, 16, 0, 0);
}

// ---------------- prep: teacher -> bf16 fragment layout ----------------
__global__ __launch_bounds__(256) void ebl_prep(
    const float* __restrict__ tp, unsigned short* __restrict__ Bp)
{
    const int idx = blockIdx.x * 256 + threadIdx.x;     // (g, c)
    if (idx >= NGRP * CP) return;
    const int g = idx / CP, c = idx - g * CP;
    unsigned short v[8];
    if (c < CD) {
        const float* p = tp + (size_t)g * 8 * CD + c;
        #pragma unroll
        for (int j = 0; j < 8; ++j) v[j] = f2bf(p[(size_t)j * CD]);
    } else {
        const unsigned short fill = (c == CD) ? 0x3F80 : 0;   // bf16(1.0) / 0
        #pragma unroll
        for (int j = 0; j < 8; ++j) v[j] = fill;
    }
    *reinterpret_cast<uint4*>(Bp + (size_t)idx * 8) = *reinterpret_cast<const uint4*>(v);
}

// ---------------- GEMM: wave-private 3-deep pipeline, 64-col tiles, 256B segments ----------------
// Per wave-phase: 32 n-rows x 64 m-cols (8 KB) staged by 8 x global_load_lds(size=16):
// instr q = rows 4q..4q+3, lane l -> row l>>4, cols (l&15)*4..+3 (256B contiguous per row).
// LDS chunk layout (linear, matches HW lane*16B dest): off(q,r,c) = q*256 + r*64 + c dwords.
__global__ __launch_bounds__(128) void ebl_gemm(
    const float* __restrict__ mem, const unsigned short* __restrict__ Bp,
    unsigned short* __restrict__ spart)
{
    __shared__ float At[3 * 2 * 2048];     // 3 bufs x 2 waves x 8 KB = 48 KB

    const int t  = threadIdx.x;
    const int w  = t >> 6;                 // wave 0..1 -> m cols [w*64, w*64+64)
    const int l  = t & 63;
    const int lg = l >> 4, lr = l & 15;
    const int m0 = blockIdx.x * 128;
    const int kc = blockIdx.y;
    const int n0 = kc * (PHASES * 32);
    const int gb = n0 >> 3;

    // per-lane global base: row n0 + (l>>4), col m0 + w*64 + (l&15)*4
    const float* gbase = mem + (size_t)(n0 + lg) * FKD + (m0 + w * 64 + lr * 4);

    f32x4 acc[4][7];
    #pragma unroll
    for (int i = 0; i < 4; ++i)
        #pragma unroll
        for (int nt = 0; nt < 7; ++nt) acc[i][nt] = (f32x4){0.f, 0.f, 0.f, 0.f};

    bf16x8 b0[7], b1[7];
    int o0 = (0 * 2 + w) * 2048, o1 = (1 * 2 + w) * 2048, o2 = (2 * 2 + w) * 2048;

#define SB() __builtin_amdgcn_sched_barrier(0)
#define STAGE(bo, p) { \
    const float* gs = gbase + (size_t)(p) * 32 * FKD; \
    _Pragma("unroll") \
    for (int q = 0; q < 8; ++q) \
        gload16(gs + (size_t)q * 4 * FKD, At + (bo) + q * 256); \
    SB(); }
#define LOADB(dst, p) { \
    const unsigned short* bq = Bp + ((size_t)(gb + (p) * 4 + lg) * CP + lr) * 8; \
    _Pragma("unroll") \
    for (int nt = 0; nt < 7; ++nt) dst[nt] = *reinterpret_cast<const bf16x8*>(bq + nt * 128); \
    SB(); }
#define WAITV(n) { asm volatile("s_waitcnt vmcnt(" #n ")" ::: "memory"); SB(); }
#define COMPUTE(bo, bB) { \
    bf16x8 af[4]; \
    _Pragma("unroll") \
    for (int i = 0; i < 4; ++i) \
        _Pragma("unroll") \
        for (int j = 0; j < 8; ++j) { \
            float v = At[(bo) + (2 * lg + (j >> 2)) * 256 + (j & 3) * 64 + i * 16 + lr]; \
            af[i][j] = (short)f2bf(v); } \
    _Pragma("unroll") \
    for (int i = 0; i < 4; ++i) \
        _Pragma("unroll") \
        for (int nt = 0; nt < 7; ++nt) \
            acc[i][nt] = __builtin_amdgcn_mfma_f32_16x16x32_bf16(af[i], bB[nt], acc[i][nt], 0, 0, 0); }

    // prologue: stage(0), B(0), stage(1)
    STAGE(o0, 0)
    LOADB(b0, 0)
    STAGE(o1, 1)

    // main: invariant at top: o0 = ph, o1 = ph+1, o2 free.  [counts identical to round 9]
    for (int ph = 0; ph < PHASES - 2; ph += 2) {
        LOADB(b1, ph + 1)
        STAGE(o2, ph + 2)
        WAITV(23)                 // stage(ph)+B(ph) done; 2 stages + 1 B stay in flight
        COMPUTE(o0, b0)
        LOADB(b0, ph + 2)
        STAGE(o0, ph + 3)
        WAITV(23)
        COMPUTE(o1, b1)
        const int tmp = o2; o2 = o1; o1 = o0; o0 = tmp;   // (o0,o1,o2) <- (o2,o0,o1)
    }
    // epilogue: phases 14, 15  (o0 = 14, o1 = 15, b0 = B(14))
    LOADB(b1, PHASES - 1)
    WAITV(15)                     // newer-than-B(14): stage(15)=8 + B(15)=7
    COMPUTE(o0, b0)
    WAITV(0)
    COMPUTE(o1, b1)

#undef SB
#undef STAGE
#undef LOADB
#undef WAITV
#undef COMPUTE

    // C/D layout: col = lane&15, row = (lane>>4)*4 + reg   [verified rounds 1-9]
    unsigned short* sp = spart + (size_t)kc * SFK;
    #pragma unroll
    for (int i = 0; i < 4; ++i) {
        #pragma unroll
        for (int nt = 0; nt < 7; ++nt) {
            const int c = nt * 16 + lr;
            #pragma unroll
            for (int r = 0; r < 4; ++r) {
                const int mm = m0 + w * 64 + i * 16 + lg * 4 + r;
                sp[(size_t)mm * CP + c] = f2bf(acc[i][nt][r]);
            }
        }
    }
}

// ---------------- reduce split-K partials (bf16 -> fp32, parallel) ----------------
__global__ __launch_bounds__(256) void ebl_reduce(
    const unsigned short* __restrict__ spart, float* __restrict__ S)
{
    const int idx = blockIdx.x * 256 + threadIdx.x;   // 2-element index
    if (idx >= SFK / 2) return;
    float s0 = 0.f, s1 = 0.f;
    for (int p = 0; p < NKC; ++p) {
        const unsigned raw = *reinterpret_cast<const unsigned*>(spart + (size_t)p * SFK + (size_t)idx * 2);
        s0 += __uint_as_float(raw << 16);
        s1 += __uint_as_float(raw & 0xFFFF0000u);
    }
    *reinterpret_cast<float2*>(S + (size_t)idx * 2) = make_float2(s0, s1);
}

// ---------------- entropies per f, partial losses ----------------
__global__ __launch_bounds__(256) void ebl_entropy(
    const float* __restrict__ S, float* __restrict__ fpart)
{
    __shared__ float Ss[32 * CP];
    __shared__ float massL[32];
    __shared__ float red[4];
    const int t = threadIdx.x;
    const int f = blockIdx.x;

    for (int idx = t; idx < 32 * CP; idx += 256)
        Ss[idx] = S[(size_t)f * 32 * CP + idx];
    __syncthreads();
    if (t < 32) massL[t] = Ss[t * CP + CD] + EPSF;   // ones-column = bin mass (+EPS)
    __syncthreads();

    float a_int = 0.f, a_mix = 0.f;
    for (int idx = t; idx < 32 * CD; idx += 256) {
        const int k = idx / CD, c = idx - k * CD;
        const float cent = Ss[k * CP + c] / massL[k];
        a_int -= cent * logf(cent + EPSF) * massL[k];
    }
    for (int idx = t; idx < 31 * CD; idx += 256) {
        const int k = idx / CD, c = idx - k * CD;
        const float mix = 0.5f * (Ss[k * CP + c] / massL[k] + Ss[(k + 1) * CP + c] / massL[k + 1]);
        a_mix += mix * logf(mix + EPSF);
    }

    float part = a_int * (1.0f / (float)NS) + 0.5f * a_mix;
    #pragma unroll
    for (int off = 32; off > 0; off >>= 1) part += __shfl_down(part, off);
    if ((t & 63) == 0) red[t >> 6] = part;
    __syncthreads();
    if (t == 0) fpart[f] = (red[0] + red[1]) + (red[2] + red[3]);
}

__global__ void ebl_finalize(const float* __restrict__ fpart, float* __restrict__ out) {
    float v = fpart[threadIdx.x];
    #pragma unroll
    for (int off = 32; off > 0; off >>= 1) v += __shfl_down(v, off);
    if (threadIdx.x == 0) out[0] = v;
}

extern "C" void kernel_launch(void* const* d_in, const int* in_sizes, int n_in,
                              void* d_out, int out_size, void* d_ws, size_t ws_size,
                              hipStream_t stream)
{
    const float* mem = (const float*)d_in[0];
    const float* tp  = (const float*)d_in[1];
    float* out = (float*)d_out;

    const size_t bpBytes = (size_t)NGRP * CP * 8 * 2;    // 3,670,016 B

    unsigned short* Bp    = (unsigned short*)d_ws;
    unsigned short* spart = (unsigned short*)((char*)d_ws + bpBytes);
    float*          S     = (float*)((char*)spart + (size_t)NKC * SFK * 2);
    float*          fpart = S + SFK;

    ebl_prep<<<(NGRP * CP + 255) / 256, 256, 0, stream>>>(tp, Bp);
    dim3 grid(FKD / 128, NKC);                           // 16 x 32 = 512 blocks, 128 thr
    ebl_gemm<<<grid, 128, 0, stream>>>(mem, Bp, spart);
    ebl_reduce<<<(SFK / 2 + 255) / 256, 256, 0, stream>>>(spart, S);
    ebl_entropy<<<64, 256, 0, stream>>>(S, fpart);
    ebl_finalize<<<1, 64, 0, stream>>>(fpart, out);
}